// Round 1
// baseline (11720.129 us; speedup 1.0000x reference)
//
#include <hip/hip_runtime.h>

typedef __attribute__((ext_vector_type(4))) short bf4;
typedef __attribute__((ext_vector_type(8))) short bf8;
typedef __attribute__((ext_vector_type(4))) float f4;

#define BB 64
#define SS 512
#define II 512
#define HH 1024
#define SCH 64     // steps per chunk
#define NCH 8      // chunks
#define GBLK 64    // persistent blocks in recurrent kernel

__device__ __forceinline__ short f2bf(float f) {
  unsigned u = __float_as_uint(f);
  u = u + 0x7fff + ((u >> 16) & 1);   // round-to-nearest-even
  return (short)(u >> 16);
}
__device__ __forceinline__ float bf2f(short s) {
  return __uint_as_float(((unsigned)(unsigned short)s) << 16);
}
__device__ __forceinline__ float sigm(float x) {
  return 1.0f / (1.0f + __expf(-x));
}
__device__ __forceinline__ float tanh_f(float x) {
  float e = __expf(-2.0f * fabsf(x));
  float t = (1.0f - e) / (1.0f + e);
  return copysignf(t, x);
}

// ---------------- prep kernels ----------------

__global__ __launch_bounds__(256) void cast_x_k(const float* __restrict__ x, short* __restrict__ xb) {
  size_t i = ((size_t)blockIdx.x * 256 + threadIdx.x) * 4;
  float4 v = *(const float4*)(x + i);
  bf4 o; o[0] = f2bf(v.x); o[1] = f2bf(v.y); o[2] = f2bf(v.z); o[3] = f2bf(v.w);
  *(bf4*)(xb + i) = o;
}

// WxT[g][n][k] = W_g[k][n]  (k<512) — bf16, n-major for GEMM B staging
__global__ __launch_bounds__(256) void prep_wxt_k(const float* __restrict__ Wz, const float* __restrict__ Wr,
                                                  const float* __restrict__ Wh, short* __restrict__ WxT) {
  int idx = blockIdx.x * 256 + threadIdx.x;           // < 3*1024*512
  int g = idx >> 19;
  int rem = idx & 524287;
  int n = rem >> 9, k = rem & 511;
  const float* W = (g == 0) ? Wz : (g == 1) ? Wr : Wh;
  WxT[idx] = f2bf(W[(size_t)k * HH + n]);
}

// Us[g][nblk][kk][lane][j] = W_g[512 + kk*32 + (lane>>4)*8 + j][nblk*16 + (lane&15)]
// pre-swizzled MFMA B-fragment layout for the recurrent kernel
__global__ __launch_bounds__(256) void prep_uswz_k(const float* __restrict__ Wz, const float* __restrict__ Wr,
                                                   const float* __restrict__ Wh, short* __restrict__ Us) {
  int t = blockIdx.x * 256 + threadIdx.x;             // < 3*64*32*64
  int lane = t & 63, kk = (t >> 6) & 31, nb = (t >> 11) & 63, g = t >> 17;
  const float* W = (g == 0) ? Wz : (g == 1) ? Wr : Wh;
  int n = nb * 16 + (lane & 15);
  int kb = II + kk * 32 + (lane >> 4) * 8;
  bf8 o;
#pragma unroll
  for (int j = 0; j < 8; j++) o[j] = f2bf(W[(size_t)(kb + j) * HH + n]);
  *(bf8*)(Us + (size_t)t * 8) = o;
}

__global__ __launch_bounds__(256) void init_h_k(const float* __restrict__ h, float* __restrict__ h32,
                                                short* __restrict__ hb) {
  int i = blockIdx.x * 256 + threadIdx.x;             // < 65536
  float v = h[i];
  h32[i] = v; hb[i] = f2bf(v);
}

// ---------------- input-projection GEMM ----------------
// C[m=(sl,b)][n=(g,h)] : M=64*SCH rows (sl = blockIdx.x, 64 b's), N=3072, K=512
// Gx layout: [sl][3][H][B] bf16, bias folded in.
__global__ __launch_bounds__(256) void gemm_k(const short* __restrict__ xb, const short* __restrict__ WxT,
                                              const float* __restrict__ bz, const float* __restrict__ br,
                                              const float* __restrict__ bh, short* __restrict__ Gx, int s0) {
  __shared__ short Al[4 * 64 * 8];
  __shared__ short Bl[4 * 64 * 8];
  int tid = threadIdx.x, wave = tid >> 6, lane = tid & 63;
  int sl = blockIdx.x;
  int n0 = blockIdx.y * 64;
  f4 acc[4] = {};
  int mp = tid >> 2, q = tid & 3;
  const short* asrc = xb + ((size_t)mp * SS + (s0 + sl)) * II + q * 8;
  int ng = n0 + mp;
  int gb = ng >> 10, hb_ = ng & 1023;
  const short* bsrc = WxT + ((size_t)gb * HH + hb_) * II + q * 8;
  int adst = ((mp >> 4) * 64 + q * 16 + (mp & 15)) * 8;

  for (int kk = 0; kk < II; kk += 32) {
    bf8 av = *(const bf8*)(asrc + kk);
    bf8 bv = *(const bf8*)(bsrc + kk);
    __syncthreads();
    *(bf8*)&Al[adst] = av;
    *(bf8*)&Bl[adst] = bv;
    __syncthreads();
    bf8 af = *(bf8*)&Al[(wave * 64 + lane) * 8];
#pragma unroll
    for (int ns = 0; ns < 4; ns++) {
      bf8 bfr = *(bf8*)&Bl[(ns * 64 + lane) * 8];
      acc[ns] = __builtin_amdgcn_mfma_f32_16x16x32_bf16(af, bfr, acc[ns], 0, 0, 0);
    }
  }
  int brow0 = wave * 16 + (lane >> 4) * 4;
#pragma unroll
  for (int ns = 0; ns < 4; ns++) {
    int ngl = n0 + ns * 16 + (lane & 15);
    int g2 = ngl >> 10, h2 = ngl & 1023;
    float bias = ((g2 == 0) ? bz : (g2 == 1) ? br : bh)[h2];
    bf4 o;
#pragma unroll
    for (int i = 0; i < 4; i++) o[i] = f2bf(acc[ns][i] + bias);
    *(bf4*)&Gx[(((size_t)sl * 3 + g2) * HH + h2) * BB + brow0] = o;
  }
}

// ---------------- persistent recurrent kernel ----------------

__device__ __forceinline__ void gbar(unsigned* flags, unsigned target) {
  __syncthreads();
  if (threadIdx.x == 0)
    __hip_atomic_store(&flags[blockIdx.x], target, __ATOMIC_RELEASE, __HIP_MEMORY_SCOPE_AGENT);
  if (threadIdx.x < GBLK) {
    while (__hip_atomic_load(&flags[threadIdx.x], __ATOMIC_ACQUIRE, __HIP_MEMORY_SCOPE_AGENT) < target)
      __builtin_amdgcn_s_sleep(2);
  }
  __syncthreads();
}

__global__ __launch_bounds__(256) void rec_k(const short* __restrict__ Gx, const short* __restrict__ Us,
                                             float* __restrict__ h32, short* __restrict__ hb,
                                             short* __restrict__ rhb, unsigned* __restrict__ flags) {
  __shared__ short Uzr[2 * 32 * 64 * 8];   // 64 KB: Uz,Ur fragments for own 16 columns
  int tid = threadIdx.x, wave = tid >> 6, lane = tid & 63, bid = blockIdx.x;
  // stage Uz/Ur fragment slices (coalesced bf8 copies)
  {
    const bf8* sz = (const bf8*)Us + ((size_t)(0 * 64 + bid)) * 2048;
    const bf8* sr = (const bf8*)Us + ((size_t)(1 * 64 + bid)) * 2048;
    bf8* d = (bf8*)Uzr;
    for (int i = tid; i < 2048; i += 256) { d[i] = sz[i]; d[2048 + i] = sr[i]; }
  }
  const bf8* Uh = (const bf8*)Us + ((size_t)(2 * 64 + bid)) * 2048;   // streamed from L2

  int n0 = bid * 16;
  int brow0 = wave * 16 + (lane >> 4) * 4;
  int ncol = n0 + (lane & 15);
  float hreg[4];                       // fp32 master h, C-fragment positions (block-private)
#pragma unroll
  for (int i = 0; i < 4; i++) hreg[i] = h32[(size_t)(brow0 + i) * HH + ncol];
  __syncthreads();

  const short* hrow  = hb  + ((size_t)(wave * 16 + (lane & 15))) * HH + (lane >> 4) * 8;
  const short* rhrow = rhb + ((size_t)(wave * 16 + (lane & 15))) * HH + (lane >> 4) * 8;

  unsigned target = 0;
  for (int t = 0; t < SCH; t++) {
    // -------- phase 1: z, r --------
    f4 zacc = {}, racc = {};
#pragma unroll 8
    for (int kk = 0; kk < 32; kk++) {
      bf8 af = *(const bf8*)(hrow + kk * 32);
      bf8 b0 = *(bf8*)&Uzr[(kk * 64 + lane) * 8];
      zacc = __builtin_amdgcn_mfma_f32_16x16x32_bf16(af, b0, zacc, 0, 0, 0);
      bf8 b1 = *(bf8*)&Uzr[(2048 + kk * 64 + lane) * 8];
      racc = __builtin_amdgcn_mfma_f32_16x16x32_bf16(af, b1, racc, 0, 0, 0);
    }
    const short* gz = Gx + (((size_t)t * 3 + 0) * HH + ncol) * BB + brow0;
    bf4 gzv = *(const bf4*)gz;
    bf4 grv = *(const bf4*)(gz + (size_t)HH * BB);
    float zf[4];
#pragma unroll
    for (int i = 0; i < 4; i++) {
      zf[i] = sigm(zacc[i] + bf2f(gzv[i]));
      float r = sigm(racc[i] + bf2f(grv[i]));
      rhb[(size_t)(brow0 + i) * HH + ncol] = f2bf(r * hreg[i]);
    }
    gbar(flags, ++target);
    // -------- phase 2: candidate + update --------
    f4 cacc = {};
#pragma unroll 8
    for (int kk = 0; kk < 32; kk++) {
      bf8 af = *(const bf8*)(rhrow + kk * 32);
      bf8 b2 = Uh[kk * 64 + lane];
      cacc = __builtin_amdgcn_mfma_f32_16x16x32_bf16(af, b2, cacc, 0, 0, 0);
    }
    bf4 ghv = *(const bf4*)(Gx + (((size_t)t * 3 + 2) * HH + ncol) * BB + brow0);
#pragma unroll
    for (int i = 0; i < 4; i++) {
      float c = tanh_f(cacc[i] + bf2f(ghv[i]));
      float hn = hreg[i] + zf[i] * (c - hreg[i]);
      hreg[i] = hn;
      hb[(size_t)(brow0 + i) * HH + ncol] = f2bf(hn);
    }
    gbar(flags, ++target);
  }
#pragma unroll
  for (int i = 0; i < 4; i++) h32[(size_t)(brow0 + i) * HH + ncol] = hreg[i];
}

// ---------------- output head ----------------

__global__ __launch_bounds__(64) void out_k(const float* __restrict__ h32, const float* __restrict__ Wfc,
                                            const float* __restrict__ bfc, float* __restrict__ out) {
  int b = blockIdx.x, t = threadIdx.x;
  float a0 = 0.f, a1 = 0.f;
  for (int k = t; k < HH; k += 64) {
    float hv = fmaxf(h32[(size_t)b * HH + k], 0.f);
    a0 += hv * Wfc[k * 2]; a1 += hv * Wfc[k * 2 + 1];
  }
#pragma unroll
  for (int off = 32; off > 0; off >>= 1) { a0 += __shfl_down(a0, off); a1 += __shfl_down(a1, off); }
  if (t == 0) {
    float y0 = a0 + bfc[0], y1 = a1 + bfc[1];
    float m = fmaxf(y0, y1);
    float lse = m + logf(__expf(y0 - m) + __expf(y1 - m));
    out[b * 2] = y0 - lse; out[b * 2 + 1] = y1 - lse;
  }
}

// ---------------- launch ----------------

extern "C" void kernel_launch(void* const* d_in, const int* in_sizes, int n_in,
                              void* d_out, int out_size, void* d_ws, size_t ws_size,
                              hipStream_t stream) {
  const float* x   = (const float*)d_in[0];
  const float* h0  = (const float*)d_in[1];
  const float* Wz  = (const float*)d_in[2];
  const float* bz  = (const float*)d_in[3];
  const float* Wr  = (const float*)d_in[4];
  const float* br  = (const float*)d_in[5];
  const float* Wh  = (const float*)d_in[6];
  const float* bh  = (const float*)d_in[7];
  const float* Wfc = (const float*)d_in[8];
  const float* bfc = (const float*)d_in[9];
  float* out = (float*)d_out;

  char* ws = (char*)d_ws;
  short*    xb    = (short*)(ws);                       // 33,554,432 B
  short*    WxT   = (short*)(ws + 33554432);            //  3,145,728 B
  short*    Us    = (short*)(ws + 36700160);            //  6,291,456 B
  short*    Gx    = (short*)(ws + 42991616);            // 25,165,824 B (one chunk)
  float*    h32   = (float*)(ws + 68157440);            //    262,144 B
  short*    hbuf  = (short*)(ws + 68419584);            //    131,072 B
  short*    rhb   = (short*)(ws + 68550656);            //    131,072 B
  unsigned* flags = (unsigned*)(ws + 68681728);         //        256 B

  cast_x_k<<<16384, 256, 0, stream>>>(x, xb);
  prep_wxt_k<<<6144, 256, 0, stream>>>(Wz, Wr, Wh, WxT);
  prep_uswz_k<<<1536, 256, 0, stream>>>(Wz, Wr, Wh, Us);
  init_h_k<<<256, 256, 0, stream>>>(h0, h32, hbuf);

  for (int c = 0; c < NCH; c++) {
    gemm_k<<<dim3(SCH, 48), 256, 0, stream>>>(xb, WxT, bz, br, bh, Gx, c * SCH);
    hipMemsetAsync(flags, 0, GBLK * sizeof(unsigned), stream);
    rec_k<<<GBLK, 256, 0, stream>>>(Gx, Us, h32, hbuf, rhb, flags);
  }
  out_k<<<BB, 64, 0, stream>>>(h32, Wfc, bfc, out);
}

// Round 2
// 11651.470 us; speedup vs baseline: 1.0059x; 1.0059x over previous
//
#include <hip/hip_runtime.h>

typedef __attribute__((ext_vector_type(4))) short bf4;
typedef __attribute__((ext_vector_type(8))) short bf8;
typedef __attribute__((ext_vector_type(4))) float f4;

#define BB 64
#define SS 512
#define II 512
#define HH 1024
#define SCH 64     // steps per chunk
#define NCH 8      // chunks
#define GBLK 64    // persistent blocks in recurrent kernel

__device__ __forceinline__ short f2bf(float f) {
  unsigned u = __float_as_uint(f);
  u = u + 0x7fff + ((u >> 16) & 1);   // round-to-nearest-even
  return (short)(u >> 16);
}
__device__ __forceinline__ float bf2f(short s) {
  return __uint_as_float(((unsigned)(unsigned short)s) << 16);
}
__device__ __forceinline__ float sigm(float x) {
  return 1.0f / (1.0f + __expf(-x));
}
__device__ __forceinline__ float tanh_f(float x) {
  float e = __expf(-2.0f * fabsf(x));
  float t = (1.0f - e) / (1.0f + e);
  return copysignf(t, x);
}

// L3-coherent (agent-scope, cache-bypassing, NO invalidate) comm primitives
__device__ __forceinline__ unsigned long long ld_u64_l3(const unsigned long long* p) {
  return __hip_atomic_load((unsigned long long*)p, __ATOMIC_RELAXED, __HIP_MEMORY_SCOPE_AGENT);
}
__device__ __forceinline__ void st_u32_l3(unsigned* p, unsigned v) {
  __hip_atomic_store(p, v, __ATOMIC_RELAXED, __HIP_MEMORY_SCOPE_AGENT);
}

// ---------------- prep kernels ----------------

__global__ __launch_bounds__(256) void cast_x_k(const float* __restrict__ x, short* __restrict__ xb) {
  size_t i = ((size_t)blockIdx.x * 256 + threadIdx.x) * 4;
  float4 v = *(const float4*)(x + i);
  bf4 o; o[0] = f2bf(v.x); o[1] = f2bf(v.y); o[2] = f2bf(v.z); o[3] = f2bf(v.w);
  *(bf4*)(xb + i) = o;
}

// WxT[g][n][k] = W_g[k][n]  (k<512) — bf16, n-major for GEMM B staging
__global__ __launch_bounds__(256) void prep_wxt_k(const float* __restrict__ Wz, const float* __restrict__ Wr,
                                                  const float* __restrict__ Wh, short* __restrict__ WxT) {
  int idx = blockIdx.x * 256 + threadIdx.x;           // < 3*1024*512
  int g = idx >> 19;
  int rem = idx & 524287;
  int n = rem >> 9, k = rem & 511;
  const float* W = (g == 0) ? Wz : (g == 1) ? Wr : Wh;
  WxT[idx] = f2bf(W[(size_t)k * HH + n]);
}

// Us[g][nblk][kk][lane][j] = W_g[512 + kk*32 + (lane>>4)*8 + j][nblk*16 + (lane&15)]
__global__ __launch_bounds__(256) void prep_uswz_k(const float* __restrict__ Wz, const float* __restrict__ Wr,
                                                   const float* __restrict__ Wh, short* __restrict__ Us) {
  int t = blockIdx.x * 256 + threadIdx.x;             // < 3*64*32*64
  int lane = t & 63, kk = (t >> 6) & 31, nb = (t >> 11) & 63, g = t >> 17;
  const float* W = (g == 0) ? Wz : (g == 1) ? Wr : Wh;
  int n = nb * 16 + (lane & 15);
  int kb = II + kk * 32 + (lane >> 4) * 8;
  bf8 o;
#pragma unroll
  for (int j = 0; j < 8; j++) o[j] = f2bf(W[(size_t)(kb + j) * HH + n]);
  *(bf8*)(Us + (size_t)t * 8) = o;
}

__global__ __launch_bounds__(256) void init_h_k(const float* __restrict__ h, float* __restrict__ h32,
                                                short* __restrict__ hb) {
  int i = blockIdx.x * 256 + threadIdx.x;             // < 65536
  float v = h[i];
  h32[i] = v; hb[i] = f2bf(v);
}

// ---------------- input-projection GEMM ----------------
__global__ __launch_bounds__(256) void gemm_k(const short* __restrict__ xb, const short* __restrict__ WxT,
                                              const float* __restrict__ bz, const float* __restrict__ br,
                                              const float* __restrict__ bh, short* __restrict__ Gx, int s0) {
  __shared__ short Al[4 * 64 * 8];
  __shared__ short Bl[4 * 64 * 8];
  int tid = threadIdx.x, wave = tid >> 6, lane = tid & 63;
  int sl = blockIdx.x;
  int n0 = blockIdx.y * 64;
  f4 acc[4] = {};
  int mp = tid >> 2, q = tid & 3;
  const short* asrc = xb + ((size_t)mp * SS + (s0 + sl)) * II + q * 8;
  int ng = n0 + mp;
  int gb = ng >> 10, hb_ = ng & 1023;
  const short* bsrc = WxT + ((size_t)gb * HH + hb_) * II + q * 8;
  int adst = ((mp >> 4) * 64 + q * 16 + (mp & 15)) * 8;

  for (int kk = 0; kk < II; kk += 32) {
    bf8 av = *(const bf8*)(asrc + kk);
    bf8 bv = *(const bf8*)(bsrc + kk);
    __syncthreads();
    *(bf8*)&Al[adst] = av;
    *(bf8*)&Bl[adst] = bv;
    __syncthreads();
    bf8 af = *(bf8*)&Al[(wave * 64 + lane) * 8];
#pragma unroll
    for (int ns = 0; ns < 4; ns++) {
      bf8 bfr = *(bf8*)&Bl[(ns * 64 + lane) * 8];
      acc[ns] = __builtin_amdgcn_mfma_f32_16x16x32_bf16(af, bfr, acc[ns], 0, 0, 0);
    }
  }
  int brow0 = wave * 16 + (lane >> 4) * 4;
#pragma unroll
  for (int ns = 0; ns < 4; ns++) {
    int ngl = n0 + ns * 16 + (lane & 15);
    int g2 = ngl >> 10, h2 = ngl & 1023;
    float bias = ((g2 == 0) ? bz : (g2 == 1) ? br : bh)[h2];
    bf4 o;
#pragma unroll
    for (int i = 0; i < 4; i++) o[i] = f2bf(acc[ns][i] + bias);
    *(bf4*)&Gx[(((size_t)sl * 3 + g2) * HH + h2) * BB + brow0] = o;
  }
}

// ---------------- persistent recurrent kernel ----------------

__device__ __forceinline__ void gbar(unsigned* flags, unsigned target) {
  __syncthreads();   // drains each wave's write-through stores (vmcnt(0) before s_barrier)
  if (threadIdx.x == 0)
    __hip_atomic_store(&flags[blockIdx.x], target, __ATOMIC_RELEASE, __HIP_MEMORY_SCOPE_AGENT);
  if (threadIdx.x < GBLK) {
    while (__hip_atomic_load(&flags[threadIdx.x], __ATOMIC_RELAXED, __HIP_MEMORY_SCOPE_AGENT) < target)
      __builtin_amdgcn_s_sleep(1);
  }
  __asm__ volatile("" ::: "memory");   // no compiler motion across the barrier
  __syncthreads();
}

union HL { unsigned long long u[2]; bf8 v; };

__global__ __launch_bounds__(256) void rec_k(const short* __restrict__ Gx, const short* __restrict__ Us,
                                             float* __restrict__ h32, short* hb,
                                             short* rhb, unsigned* flags) {
  __shared__ short Uzr[2 * 32 * 64 * 8];   // 64 KB: Uz,Ur fragments for own 16 columns
  int tid = threadIdx.x, wave = tid >> 6, lane = tid & 63, bid = blockIdx.x;
  {
    const bf8* sz = (const bf8*)Us + ((size_t)(0 * 64 + bid)) * 2048;
    const bf8* sr = (const bf8*)Us + ((size_t)(1 * 64 + bid)) * 2048;
    bf8* d = (bf8*)Uzr;
    for (int i = tid; i < 2048; i += 256) { d[i] = sz[i]; d[2048 + i] = sr[i]; }
  }
  const bf8* Uh = (const bf8*)Us + ((size_t)(2 * 64 + bid)) * 2048;   // L2-resident (no invalidates now)

  int n0 = bid * 16;
  int brow0 = wave * 16 + (lane >> 4) * 4;
  int ncol = n0 + (lane & 15);
  float hreg[4];                       // fp32 master h, C-fragment positions (block-private)
#pragma unroll
  for (int i = 0; i < 4; i++) hreg[i] = h32[(size_t)(brow0 + i) * HH + ncol];
  __syncthreads();

  // u64 base offsets into hb/rhb for A-fragment reads (16B/lane/kk as 2x8B)
  size_t aoff = ((size_t)(wave * 16 + (lane & 15)) * HH + (lane >> 4) * 8) / 4;
  const unsigned long long* hq  = (const unsigned long long*)hb  + aoff;
  const unsigned long long* rhq = (const unsigned long long*)rhb + aoff;

  unsigned target = 0;
  for (int t = 0; t < SCH; t++) {
    // -------- phase 1: z, r --------
    const short* gz = Gx + (((size_t)t * 3 + 0) * HH + ncol) * BB + brow0;
    bf4 gzv = *(const bf4*)gz;                       // normal cached loads, issued early
    bf4 grv = *(const bf4*)(gz + (size_t)HH * BB);
    bf4 ghv = *(const bf4*)(gz + 2 * (size_t)HH * BB);  // prefetch for phase 2 (crosses barrier)
    f4 zacc = {}, racc = {};
#pragma unroll
    for (int g = 0; g < 4; g++) {                    // batch 8 kk of L3 loads, then 16 MFMAs
      HL a[8];
#pragma unroll
      for (int j = 0; j < 8; j++) {
        int kk = g * 8 + j;
        a[j].u[0] = ld_u64_l3(hq + kk * 8);
        a[j].u[1] = ld_u64_l3(hq + kk * 8 + 1);
      }
#pragma unroll
      for (int j = 0; j < 8; j++) {
        int kk = g * 8 + j;
        bf8 b0 = *(bf8*)&Uzr[(kk * 64 + lane) * 8];
        zacc = __builtin_amdgcn_mfma_f32_16x16x32_bf16(a[j].v, b0, zacc, 0, 0, 0);
        bf8 b1 = *(bf8*)&Uzr[(2048 + kk * 64 + lane) * 8];
        racc = __builtin_amdgcn_mfma_f32_16x16x32_bf16(a[j].v, b1, racc, 0, 0, 0);
      }
    }
    float zf[4];
#pragma unroll
    for (int i = 0; i < 4; i++) {
      zf[i] = sigm(zacc[i] + bf2f(gzv[i]));
      float r = sigm(racc[i] + bf2f(grv[i]));
      unsigned sv = (unsigned)(unsigned short)f2bf(r * hreg[i]);
      unsigned up = __shfl_down(sv, 1);
      if (!(lane & 1))                               // packed 4B write-through store
        st_u32_l3((unsigned*)rhb + ((size_t)(brow0 + i) * HH + ncol) / 2, sv | (up << 16));
    }
    gbar(flags, ++target);
    // -------- phase 2: candidate + update --------
    f4 cacc = {};
#pragma unroll
    for (int g = 0; g < 4; g++) {
      HL a[8];
#pragma unroll
      for (int j = 0; j < 8; j++) {
        int kk = g * 8 + j;
        a[j].u[0] = ld_u64_l3(rhq + kk * 8);
        a[j].u[1] = ld_u64_l3(rhq + kk * 8 + 1);
      }
#pragma unroll
      for (int j = 0; j < 8; j++) {
        int kk = g * 8 + j;
        bf8 b2 = Uh[kk * 64 + lane];                 // normal load, L2-hit
        cacc = __builtin_amdgcn_mfma_f32_16x16x32_bf16(a[j].v, b2, cacc, 0, 0, 0);
      }
    }
#pragma unroll
    for (int i = 0; i < 4; i++) {
      float c = tanh_f(cacc[i] + bf2f(ghv[i]));
      float hn = hreg[i] + zf[i] * (c - hreg[i]);
      hreg[i] = hn;
      unsigned sv = (unsigned)(unsigned short)f2bf(hn);
      unsigned up = __shfl_down(sv, 1);
      if (!(lane & 1))
        st_u32_l3((unsigned*)hb + ((size_t)(brow0 + i) * HH + ncol) / 2, sv | (up << 16));
    }
    gbar(flags, ++target);
  }
#pragma unroll
  for (int i = 0; i < 4; i++) h32[(size_t)(brow0 + i) * HH + ncol] = hreg[i];
}

// ---------------- output head ----------------

__global__ __launch_bounds__(64) void out_k(const float* __restrict__ h32, const float* __restrict__ Wfc,
                                            const float* __restrict__ bfc, float* __restrict__ out) {
  int b = blockIdx.x, t = threadIdx.x;
  float a0 = 0.f, a1 = 0.f;
  for (int k = t; k < HH; k += 64) {
    float hv = fmaxf(h32[(size_t)b * HH + k], 0.f);
    a0 += hv * Wfc[k * 2]; a1 += hv * Wfc[k * 2 + 1];
  }
#pragma unroll
  for (int off = 32; off > 0; off >>= 1) { a0 += __shfl_down(a0, off); a1 += __shfl_down(a1, off); }
  if (t == 0) {
    float y0 = a0 + bfc[0], y1 = a1 + bfc[1];
    float m = fmaxf(y0, y1);
    float lse = m + logf(__expf(y0 - m) + __expf(y1 - m));
    out[b * 2] = y0 - lse; out[b * 2 + 1] = y1 - lse;
  }
}

// ---------------- launch ----------------

extern "C" void kernel_launch(void* const* d_in, const int* in_sizes, int n_in,
                              void* d_out, int out_size, void* d_ws, size_t ws_size,
                              hipStream_t stream) {
  const float* x   = (const float*)d_in[0];
  const float* h0  = (const float*)d_in[1];
  const float* Wz  = (const float*)d_in[2];
  const float* bz  = (const float*)d_in[3];
  const float* Wr  = (const float*)d_in[4];
  const float* br  = (const float*)d_in[5];
  const float* Wh  = (const float*)d_in[6];
  const float* bh  = (const float*)d_in[7];
  const float* Wfc = (const float*)d_in[8];
  const float* bfc = (const float*)d_in[9];
  float* out = (float*)d_out;

  char* ws = (char*)d_ws;
  short*    xb    = (short*)(ws);                       // 33,554,432 B
  short*    WxT   = (short*)(ws + 33554432);            //  3,145,728 B
  short*    Us    = (short*)(ws + 36700160);            //  6,291,456 B
  short*    Gx    = (short*)(ws + 42991616);            // 25,165,824 B (one chunk)
  float*    h32   = (float*)(ws + 68157440);            //    262,144 B
  short*    hbuf  = (short*)(ws + 68419584);            //    131,072 B
  short*    rhb   = (short*)(ws + 68550656);            //    131,072 B
  unsigned* flags = (unsigned*)(ws + 68681728);         //        256 B

  cast_x_k<<<16384, 256, 0, stream>>>(x, xb);
  prep_wxt_k<<<6144, 256, 0, stream>>>(Wz, Wr, Wh, WxT);
  prep_uswz_k<<<1536, 256, 0, stream>>>(Wz, Wr, Wh, Us);
  init_h_k<<<256, 256, 0, stream>>>(h0, h32, hbuf);

  for (int c = 0; c < NCH; c++) {
    gemm_k<<<dim3(SCH, 48), 256, 0, stream>>>(xb, WxT, bz, br, bh, Gx, c * SCH);
    hipMemsetAsync(flags, 0, GBLK * sizeof(unsigned), stream);
    rec_k<<<GBLK, 256, 0, stream>>>(Gx, Us, h32, hbuf, rhb, flags);
  }
  out_k<<<BB, 64, 0, stream>>>(h32, Wfc, bfc, out);
}

// Round 3
// 10452.931 us; speedup vs baseline: 1.1212x; 1.1147x over previous
//
#include <hip/hip_runtime.h>

typedef __attribute__((ext_vector_type(4))) short bf4;
typedef __attribute__((ext_vector_type(8))) short bf8;
typedef __attribute__((ext_vector_type(4))) float f4;

#define BB 64
#define SS 512
#define II 512
#define HH 1024
#define SCH 64     // steps per chunk
#define NCH 8      // chunks
#define GBLK 64    // persistent blocks in recurrent kernel

// flags region layout (dword indices, 128-B stride to avoid line contention)
#define F_GINIT 0
#define F_XCNT  32    // +32*i
#define F_XARR  320   // +32*i
#define F_XFLAG 608   // +32*i

__device__ __forceinline__ short f2bf(float f) {
  unsigned u = __float_as_uint(f);
  u = u + 0x7fff + ((u >> 16) & 1);   // round-to-nearest-even
  return (short)(u >> 16);
}
__device__ __forceinline__ float bf2f(short s) {
  return __uint_as_float(((unsigned)(unsigned short)s) << 16);
}
__device__ __forceinline__ float sigm(float x) {
  return 1.0f / (1.0f + __expf(-x));
}
__device__ __forceinline__ float tanh_f(float x) {
  float e = __expf(-2.0f * fabsf(x));
  float t = (1.0f - e) / (1.0f + e);
  return copysignf(t, x);
}

__device__ __forceinline__ unsigned long long ld_u64_l3(const unsigned long long* p) {
  return __hip_atomic_load((unsigned long long*)p, __ATOMIC_RELAXED, __HIP_MEMORY_SCOPE_AGENT);
}
__device__ __forceinline__ void st_u32_l3(unsigned* p, unsigned v) {
  __hip_atomic_store(p, v, __ATOMIC_RELAXED, __HIP_MEMORY_SCOPE_AGENT);
}
// coherent read: RMW(+0) executes at the coherence point — never stale
__device__ __forceinline__ unsigned rmw_read(unsigned* p) {
  return __hip_atomic_fetch_add(p, 0u, __ATOMIC_RELAXED, __HIP_MEMORY_SCOPE_AGENT);
}
__device__ __forceinline__ unsigned rmw_add1(unsigned* p) {
  return __hip_atomic_fetch_add(p, 1u, __ATOMIC_RELAXED, __HIP_MEMORY_SCOPE_AGENT);
}

// ---------------- prep kernels ----------------

__global__ __launch_bounds__(256) void cast_x_k(const float* __restrict__ x, short* __restrict__ xb) {
  size_t i = ((size_t)blockIdx.x * 256 + threadIdx.x) * 4;
  float4 v = *(const float4*)(x + i);
  bf4 o; o[0] = f2bf(v.x); o[1] = f2bf(v.y); o[2] = f2bf(v.z); o[3] = f2bf(v.w);
  *(bf4*)(xb + i) = o;
}

__global__ __launch_bounds__(256) void prep_wxt_k(const float* __restrict__ Wz, const float* __restrict__ Wr,
                                                  const float* __restrict__ Wh, short* __restrict__ WxT) {
  int idx = blockIdx.x * 256 + threadIdx.x;           // < 3*1024*512
  int g = idx >> 19;
  int rem = idx & 524287;
  int n = rem >> 9, k = rem & 511;
  const float* W = (g == 0) ? Wz : (g == 1) ? Wr : Wh;
  WxT[idx] = f2bf(W[(size_t)k * HH + n]);
}

__global__ __launch_bounds__(256) void prep_uswz_k(const float* __restrict__ Wz, const float* __restrict__ Wr,
                                                   const float* __restrict__ Wh, short* __restrict__ Us) {
  int t = blockIdx.x * 256 + threadIdx.x;             // < 3*64*32*64
  int lane = t & 63, kk = (t >> 6) & 31, nb = (t >> 11) & 63, g = t >> 17;
  const float* W = (g == 0) ? Wz : (g == 1) ? Wr : Wh;
  int n = nb * 16 + (lane & 15);
  int kb = II + kk * 32 + (lane >> 4) * 8;
  bf8 o;
#pragma unroll
  for (int j = 0; j < 8; j++) o[j] = f2bf(W[(size_t)(kb + j) * HH + n]);
  *(bf8*)(Us + (size_t)t * 8) = o;
}

__global__ __launch_bounds__(256) void init_h_k(const float* __restrict__ h, float* __restrict__ h32,
                                                short* __restrict__ hb) {
  int i = blockIdx.x * 256 + threadIdx.x;             // < 65536
  float v = h[i];
  h32[i] = v; hb[i] = f2bf(v);
}

// ---------------- input-projection GEMM ----------------
__global__ __launch_bounds__(256) void gemm_k(const short* __restrict__ xb, const short* __restrict__ WxT,
                                              const float* __restrict__ bz, const float* __restrict__ br,
                                              const float* __restrict__ bh, short* __restrict__ Gx, int s0) {
  __shared__ short Al[4 * 64 * 8];
  __shared__ short Bl[4 * 64 * 8];
  int tid = threadIdx.x, wave = tid >> 6, lane = tid & 63;
  int sl = blockIdx.x;
  int n0 = blockIdx.y * 64;
  f4 acc[4] = {};
  int mp = tid >> 2, q = tid & 3;
  const short* asrc = xb + ((size_t)mp * SS + (s0 + sl)) * II + q * 8;
  int ng = n0 + mp;
  int gb = ng >> 10, hb_ = ng & 1023;
  const short* bsrc = WxT + ((size_t)gb * HH + hb_) * II + q * 8;
  int adst = ((mp >> 4) * 64 + q * 16 + (mp & 15)) * 8;

  for (int kk = 0; kk < II; kk += 32) {
    bf8 av = *(const bf8*)(asrc + kk);
    bf8 bv = *(const bf8*)(bsrc + kk);
    __syncthreads();
    *(bf8*)&Al[adst] = av;
    *(bf8*)&Bl[adst] = bv;
    __syncthreads();
    bf8 af = *(bf8*)&Al[(wave * 64 + lane) * 8];
#pragma unroll
    for (int ns = 0; ns < 4; ns++) {
      bf8 bfr = *(bf8*)&Bl[(ns * 64 + lane) * 8];
      acc[ns] = __builtin_amdgcn_mfma_f32_16x16x32_bf16(af, bfr, acc[ns], 0, 0, 0);
    }
  }
  int brow0 = wave * 16 + (lane >> 4) * 4;
#pragma unroll
  for (int ns = 0; ns < 4; ns++) {
    int ngl = n0 + ns * 16 + (lane & 15);
    int g2 = ngl >> 10, h2 = ngl & 1023;
    float bias = ((g2 == 0) ? bz : (g2 == 1) ? br : bh)[h2];
    bf4 o;
#pragma unroll
    for (int i = 0; i < 4; i++) o[i] = f2bf(acc[ns][i] + bias);
    *(bf4*)&Gx[(((size_t)sl * 3 + g2) * HH + h2) * BB + brow0] = o;
  }
}

// ---------------- persistent recurrent kernel ----------------
// Barrier: per-XCD aggregated release. All XCD-sibling stores are in that XCD's
// L2 after their __syncthreads (vmcnt(0)); the LAST arriver (relaxed RMW count)
// issues ONE buffer_wbl2 for the whole XCD, then bumps the XCD phase flag.
// Consumers poll flags with fetch_add(+0) RMWs (coherent by construction).

union HL { unsigned long long u[2]; bf8 v; };

__global__ __launch_bounds__(256) void rec_k(const short* __restrict__ Gx, const short* __restrict__ Us,
                                             float* __restrict__ h32, short* hb,
                                             short* rhb, unsigned* flags) {
  __shared__ short Uzr[2 * 32 * 64 * 8];   // 64 KB: Uz,Ur fragments for own 16 columns
  int tid = threadIdx.x, wave = tid >> 6, lane = tid & 63, bid = blockIdx.x;

  unsigned myxcc;
  __asm__ volatile("s_getreg_b32 %0, hwreg(HW_REG_XCC_ID)" : "=s"(myxcc));
  myxcc &= 7;

  // register this block's XCD (coherence-point RMWs)
  if (tid == 0) {
    rmw_add1(&flags[F_XCNT + 32 * myxcc]);
    rmw_add1(&flags[F_GINIT]);
  }

  // stage Uz/Ur fragment slices while registration propagates
  {
    const bf8* sz = (const bf8*)Us + ((size_t)(0 * 64 + bid)) * 2048;
    const bf8* sr = (const bf8*)Us + ((size_t)(1 * 64 + bid)) * 2048;
    bf8* d = (bf8*)Uzr;
    for (int i = tid; i < 2048; i += 256) { d[i] = sz[i]; d[2048 + i] = sr[i]; }
  }
  const bf8* Uh = (const bf8*)Us + ((size_t)(2 * 64 + bid)) * 2048;   // L2-resident

  int n0 = bid * 16;
  int brow0 = wave * 16 + (lane >> 4) * 4;
  int ncol = n0 + (lane & 15);
  float hreg[4];
#pragma unroll
  for (int i = 0; i < 4; i++) hreg[i] = h32[(size_t)(brow0 + i) * HH + ncol];

  // wait until all 64 blocks registered; snapshot per-XCD populations
  unsigned pres = 0, nown = 0;
  if (tid < 8) {
    while (rmw_read(&flags[F_GINIT]) < GBLK) __builtin_amdgcn_s_sleep(2);
    pres = rmw_read(&flags[F_XCNT + 32 * tid]);
    if (tid == 0) nown = rmw_read(&flags[F_XCNT + 32 * myxcc]);
  }
  __syncthreads();

  size_t aoff = ((size_t)(wave * 16 + (lane & 15)) * HH + (lane >> 4) * 8) / 4;
  const unsigned long long* hq  = (const unsigned long long*)hb  + aoff;
  const unsigned long long* rhq = (const unsigned long long*)rhb + aoff;

  unsigned target = 0;
  for (int t = 0; t < SCH; t++) {
    // -------- phase 1: z, r --------
    const short* gz = Gx + (((size_t)t * 3 + 0) * HH + ncol) * BB + brow0;
    bf4 gzv = *(const bf4*)gz;
    bf4 grv = *(const bf4*)(gz + (size_t)HH * BB);
    bf4 ghv = *(const bf4*)(gz + 2 * (size_t)HH * BB);  // prefetch for phase 2
    f4 zacc = {}, racc = {};
#pragma unroll
    for (int g = 0; g < 4; g++) {
      HL a[8];
#pragma unroll
      for (int j = 0; j < 8; j++) {
        int kk = g * 8 + j;
        a[j].u[0] = ld_u64_l3(hq + kk * 8);
        a[j].u[1] = ld_u64_l3(hq + kk * 8 + 1);
      }
#pragma unroll
      for (int j = 0; j < 8; j++) {
        int kk = g * 8 + j;
        bf8 b0 = *(bf8*)&Uzr[(kk * 64 + lane) * 8];
        zacc = __builtin_amdgcn_mfma_f32_16x16x32_bf16(a[j].v, b0, zacc, 0, 0, 0);
        bf8 b1 = *(bf8*)&Uzr[(2048 + kk * 64 + lane) * 8];
        racc = __builtin_amdgcn_mfma_f32_16x16x32_bf16(a[j].v, b1, racc, 0, 0, 0);
      }
    }
    float zf[4];
#pragma unroll
    for (int i = 0; i < 4; i++) {
      zf[i] = sigm(zacc[i] + bf2f(gzv[i]));
      float r = sigm(racc[i] + bf2f(grv[i]));
      unsigned sv = (unsigned)(unsigned short)f2bf(r * hreg[i]);
      unsigned up = __shfl_down(sv, 1);
      if (!(lane & 1))
        st_u32_l3((unsigned*)rhb + ((size_t)(brow0 + i) * HH + ncol) / 2, sv | (up << 16));
    }
    // ---- barrier A ----
    ++target;
    __syncthreads();                     // drains all waves' stores into L2
    if (tid == 0) {
      unsigned old = rmw_add1(&flags[F_XARR + 32 * myxcc]);
      if (old + 1 == nown * target) {    // last arriver of this XCD, this phase
        __asm__ volatile("buffer_wbl2 sc1" ::: "memory");
        __asm__ volatile("s_waitcnt vmcnt(0)" ::: "memory");
        rmw_add1(&flags[F_XFLAG + 32 * myxcc]);
      }
    }
    if (tid < 8 && pres)
      while (rmw_read(&flags[F_XFLAG + 32 * tid]) < target) __builtin_amdgcn_s_sleep(2);
    __asm__ volatile("" ::: "memory");
    __syncthreads();
    // -------- phase 2: candidate + update --------
    f4 cacc = {};
#pragma unroll
    for (int g = 0; g < 4; g++) {
      HL a[8];
#pragma unroll
      for (int j = 0; j < 8; j++) {
        int kk = g * 8 + j;
        a[j].u[0] = ld_u64_l3(rhq + kk * 8);
        a[j].u[1] = ld_u64_l3(rhq + kk * 8 + 1);
      }
#pragma unroll
      for (int j = 0; j < 8; j++) {
        int kk = g * 8 + j;
        bf8 b2 = Uh[kk * 64 + lane];
        cacc = __builtin_amdgcn_mfma_f32_16x16x32_bf16(a[j].v, b2, cacc, 0, 0, 0);
      }
    }
#pragma unroll
    for (int i = 0; i < 4; i++) {
      float c = tanh_f(cacc[i] + bf2f(ghv[i]));
      float hn = hreg[i] + zf[i] * (c - hreg[i]);
      hreg[i] = hn;
      unsigned sv = (unsigned)(unsigned short)f2bf(hn);
      unsigned up = __shfl_down(sv, 1);
      if (!(lane & 1))
        st_u32_l3((unsigned*)hb + ((size_t)(brow0 + i) * HH + ncol) / 2, sv | (up << 16));
    }
    // ---- barrier B ----
    ++target;
    __syncthreads();
    if (tid == 0) {
      unsigned old = rmw_add1(&flags[F_XARR + 32 * myxcc]);
      if (old + 1 == nown * target) {
        __asm__ volatile("buffer_wbl2 sc1" ::: "memory");
        __asm__ volatile("s_waitcnt vmcnt(0)" ::: "memory");
        rmw_add1(&flags[F_XFLAG + 32 * myxcc]);
      }
    }
    if (tid < 8 && pres)
      while (rmw_read(&flags[F_XFLAG + 32 * tid]) < target) __builtin_amdgcn_s_sleep(2);
    __asm__ volatile("" ::: "memory");
    __syncthreads();
  }
#pragma unroll
  for (int i = 0; i < 4; i++) h32[(size_t)(brow0 + i) * HH + ncol] = hreg[i];
}

// ---------------- output head ----------------

__global__ __launch_bounds__(64) void out_k(const float* __restrict__ h32, const float* __restrict__ Wfc,
                                            const float* __restrict__ bfc, float* __restrict__ out) {
  int b = blockIdx.x, t = threadIdx.x;
  float a0 = 0.f, a1 = 0.f;
  for (int k = t; k < HH; k += 64) {
    float hv = fmaxf(h32[(size_t)b * HH + k], 0.f);
    a0 += hv * Wfc[k * 2]; a1 += hv * Wfc[k * 2 + 1];
  }
#pragma unroll
  for (int off = 32; off > 0; off >>= 1) { a0 += __shfl_down(a0, off); a1 += __shfl_down(a1, off); }
  if (t == 0) {
    float y0 = a0 + bfc[0], y1 = a1 + bfc[1];
    float m = fmaxf(y0, y1);
    float lse = m + logf(__expf(y0 - m) + __expf(y1 - m));
    out[b * 2] = y0 - lse; out[b * 2 + 1] = y1 - lse;
  }
}

// ---------------- launch ----------------

extern "C" void kernel_launch(void* const* d_in, const int* in_sizes, int n_in,
                              void* d_out, int out_size, void* d_ws, size_t ws_size,
                              hipStream_t stream) {
  const float* x   = (const float*)d_in[0];
  const float* h0  = (const float*)d_in[1];
  const float* Wz  = (const float*)d_in[2];
  const float* bz  = (const float*)d_in[3];
  const float* Wr  = (const float*)d_in[4];
  const float* br  = (const float*)d_in[5];
  const float* Wh  = (const float*)d_in[6];
  const float* bh  = (const float*)d_in[7];
  const float* Wfc = (const float*)d_in[8];
  const float* bfc = (const float*)d_in[9];
  float* out = (float*)d_out;

  char* ws = (char*)d_ws;
  short*    xb    = (short*)(ws);                       // 33,554,432 B
  short*    WxT   = (short*)(ws + 33554432);            //  3,145,728 B
  short*    Us    = (short*)(ws + 36700160);            //  6,291,456 B
  short*    Gx    = (short*)(ws + 42991616);            // 25,165,824 B (one chunk)
  float*    h32   = (float*)(ws + 68157440);            //    262,144 B
  short*    hbuf  = (short*)(ws + 68419584);            //    131,072 B
  short*    rhb   = (short*)(ws + 68550656);            //    131,072 B
  unsigned* flags = (unsigned*)(ws + 68681728);         //      4,096 B

  cast_x_k<<<16384, 256, 0, stream>>>(x, xb);
  prep_wxt_k<<<6144, 256, 0, stream>>>(Wz, Wr, Wh, WxT);
  prep_uswz_k<<<1536, 256, 0, stream>>>(Wz, Wr, Wh, Us);
  init_h_k<<<256, 256, 0, stream>>>(h0, h32, hbuf);

  for (int c = 0; c < NCH; c++) {
    gemm_k<<<dim3(SCH, 48), 256, 0, stream>>>(xb, WxT, bz, br, bh, Gx, c * SCH);
    hipMemsetAsync(flags, 0, 4096, stream);
    rec_k<<<GBLK, 256, 0, stream>>>(Gx, Us, h32, hbuf, rhb, flags);
  }
  out_k<<<BB, 64, 0, stream>>>(h32, Wfc, bfc, out);
}